// Round 2
// baseline (2619.694 us; speedup 1.0000x reference)
//
#include <hip/hip_runtime.h>
#include <hip/hip_fp16.h>
#include <math.h>

// ---------------------------------------------------------------------------
// Sizes
// ---------------------------------------------------------------------------
#define NB   512
#define TT   60
#define FF   5
#define HH   128
#define G4   512
#define NN   2500
#define KK   50

#define O0 800
#define O1 1500
#define O2 2100

// workspace layout (float offsets)
#define OFF_WA    0                        // whh0 fp16 packed: 65536 halves = 32768 floats
#define OFF_WC    32768                    // wih1+whh1 fp16 packed: 131072 halves = 65536 floats
#define OFF_W0T   98304                    // 2560 floats (fp32, W_ih0 transposed)
#define OFF_B0    100864                   // 512
#define OFF_B1    101376                   // 512
#define OFF_A     101888                   // 2500
#define OFF_FS    104388                   // 512
#define OFF_NO    104900                   // 512*2500 (byte off 419600 %16==0)
#define OFF_MEANS (OFF_NO + NB*NN)         // 2048
#define OFF_H1    (OFF_MEANS + 2048)       // 512*256

#define PREP_TOTAL 202692                  // 65536 + 131072 + 2560 + 512 + 512 + 2500

__device__ __forceinline__ float sigf(float x) {
    return 1.0f / (1.0f + __expf(-x));
}
__device__ __forceinline__ float tanh_fast(float x) {
    float t = __expf(-2.0f * fabsf(x));
    float r = (1.0f - t) / (1.0f + t);
    return copysignf(r, x);
}

// ---------------------------------------------------------------------------
// K0: prep.
// wA fp16 layout: i = k2*1024 + j*4 + kk*2 + gh   -> W_hh0[(gh*256+j)*128 + 2*k2+kk]
// wC fp16 layout: i = k2*2048 + j*8 + m*4 + kk*2 + gh, m=0:W_ih1 m=1:W_hh1
// ---------------------------------------------------------------------------
__global__ __launch_bounds__(256) void prep_kernel(
    const float* __restrict__ W_ih0, const float* __restrict__ W_hh0,
    const float* __restrict__ b_ih0, const float* __restrict__ b_hh0,
    const float* __restrict__ W_ih1, const float* __restrict__ W_hh1,
    const float* __restrict__ b_ih1, const float* __restrict__ b_hh1,
    const float* __restrict__ conn_w, const float* __restrict__ sens,
    float* __restrict__ ws)
{
    int i = blockIdx.x * 256 + threadIdx.x;
    if (i >= PREP_TOTAL) return;

    __half* wa = (__half*)(ws + OFF_WA);
    __half* wc = (__half*)(ws + OFF_WC);

    if (i < 65536) {
        int k2 = i >> 10, rem = i & 1023, j = rem >> 2, sl = rem & 3;
        int kk = sl >> 1, gh = sl & 1;
        wa[i] = __float2half(W_hh0[(gh * 256 + j) * HH + (k2 * 2 + kk)]);
    } else if (i < 196608) {
        int v = i - 65536;
        int k2 = v >> 11, rem = v & 2047, j = rem >> 3, sl = rem & 7;
        int m = sl >> 2, kk = (sl >> 1) & 1, gh = sl & 1;
        const float* src = m ? W_hh1 : W_ih1;
        wc[v] = __float2half(src[(gh * 256 + j) * HH + (k2 * 2 + kk)]);
    } else if (i < 199168) {               // W0T[f][g] = W_ih0[g][f]
        int v = i - 196608;
        int f = v >> 9, g = v & 511;
        ws[OFF_W0T + v] = W_ih0[g * FF + f];
    } else if (i < 199680) {
        int j = i - 199168;
        ws[OFF_B0 + j] = b_ih0[j] + b_hh0[j];
    } else if (i < 200192) {
        int j = i - 199680;
        ws[OFF_B1 + j] = b_ih1[j] + b_hh1[j];
    } else {
        int n = i - 200192;
        float s = 0.f;
        const float* cw = conn_w + n * KK;
        for (int k = 0; k < KK; ++k) s += cw[k];
        ws[OFF_A + n] = s * sens[n];
    }
}

// ---------------------------------------------------------------------------
// K1: fused 2-layer LSTM + feature head.
// 256 blocks x 1024 threads, 2 batch rows/block.
// tid -> (j = tid&255: gate columns j and j+256, kq = tid>>8: k-quarter).
// Per k2 (pair of k): 1 global fp16 packed load + 1 LDS b128 h read + 8/16 fma_mix.
// Partials reduced through gp[16][256] LDS; update threads (tid<256) own (r,u) state.
// ---------------------------------------------------------------------------
__global__ __launch_bounds__(1024, 4) void lstm_fused(
    const float* __restrict__ x,
    const float* __restrict__ ws_ro,
    const float* __restrict__ fp_w1, const float* __restrict__ fp_b1,
    const float* __restrict__ fp_w2, const float* __restrict__ fp_b2,
    float* __restrict__ feat_sum)
{
    __shared__ float xs[2][TT * FF + 4];
    __shared__ __align__(16) float hb0[256];    // [k>>1][k&1][r]
    __shared__ __align__(16) float hb1[256];
    __shared__ float gp[16 * 256];              // [(kq*4 + gh*2 + r)][j]
    __shared__ float b0s[512], b1s[512];
    __shared__ float w0s[2560];
    __shared__ float t1s[2][64];
    __shared__ float bss[2][32];

    const int tid = threadIdx.x;
    const int j = tid & 255;
    const int kq = tid >> 8;
    const int brow = blockIdx.x * 2;

    for (int i = tid; i < 2 * TT * FF; i += 1024) {
        int r = i / (TT * FF), c = i % (TT * FF);
        xs[r][c] = x[(brow + r) * (TT * FF) + c];
    }
    if (tid < 256) { hb0[tid] = 0.f; hb1[tid] = 0.f; }
    if (tid < 512) { b0s[tid] = ws_ro[OFF_B0 + tid]; b1s[tid] = ws_ro[OFF_B1 + tid]; }
    for (int i = tid; i < 2560; i += 1024) w0s[i] = ws_ro[OFF_W0T + i];

    float c0 = 0.f, c1 = 0.f;
    const int ur = (tid >> 7) & 1, uk = tid & 127;

    __syncthreads();

    const uint2* wAp = (const uint2*)(ws_ro + OFF_WA) + kq * 16 * 256 + j;
    const uint4* wCp = (const uint4*)(ws_ro + OFF_WC) + kq * 16 * 256 + j;
    const float4* h0v = (const float4*)hb0 + kq * 16;
    const float4* h1v = (const float4*)hb1 + kq * 16;

    for (int t = 0; t < TT; ++t) {
        // ---------- Phase A: layer-0 partial gates ----------
        float a00 = 0.f, a01 = 0.f, a10 = 0.f, a11 = 0.f;
#pragma unroll
        for (int k2 = 0; k2 < 16; ++k2) {
            uint2 wv = wAp[k2 * 256];
            float4 h4 = h0v[k2];
            const __half* wh = (const __half*)&wv;
            a00 = fmaf(__half2float(wh[0]), h4.x, a00);
            a01 = fmaf(__half2float(wh[0]), h4.y, a01);
            a10 = fmaf(__half2float(wh[1]), h4.x, a10);
            a11 = fmaf(__half2float(wh[1]), h4.y, a11);
            a00 = fmaf(__half2float(wh[2]), h4.z, a00);
            a01 = fmaf(__half2float(wh[2]), h4.w, a01);
            a10 = fmaf(__half2float(wh[3]), h4.z, a10);
            a11 = fmaf(__half2float(wh[3]), h4.w, a11);
        }
        if (kq == 0) {
            const float* xr0 = &xs[0][t * FF];
            const float* xr1 = &xs[1][t * FF];
#pragma unroll
            for (int f = 0; f < FF; ++f) {
                float wa = w0s[f * G4 + j], wb = w0s[f * G4 + 256 + j];
                a00 = fmaf(wa, xr0[f], a00);
                a01 = fmaf(wa, xr1[f], a01);
                a10 = fmaf(wb, xr0[f], a10);
                a11 = fmaf(wb, xr1[f], a11);
            }
        }
        gp[(kq * 4 + 0) * 256 + j] = a00;
        gp[(kq * 4 + 1) * 256 + j] = a01;
        gp[(kq * 4 + 2) * 256 + j] = a10;
        gp[(kq * 4 + 3) * 256 + j] = a11;
        __syncthreads();

        // ---------- Phase B: layer-0 state update ----------
        if (tid < 256) {
            float ip = b0s[uk], fp = b0s[128 + uk], gg = b0s[256 + uk], op = b0s[384 + uk];
#pragma unroll
            for (int q = 0; q < 4; ++q) {
                ip += gp[(q * 4 + ur) * 256 + uk];
                fp += gp[(q * 4 + ur) * 256 + 128 + uk];
                gg += gp[(q * 4 + 2 + ur) * 256 + uk];
                op += gp[(q * 4 + 2 + ur) * 256 + 128 + uk];
            }
            c0 = sigf(fp) * c0 + sigf(ip) * tanh_fast(gg);
            hb0[(uk >> 1) * 4 + (uk & 1) * 2 + ur] = sigf(op) * tanh_fast(c0);
        }
        __syncthreads();

        // ---------- Phase C: layer-1 partial gates (Wih1@h0 + Whh1@h1) ----------
        a00 = 0.f; a01 = 0.f; a10 = 0.f; a11 = 0.f;
#pragma unroll
        for (int k2 = 0; k2 < 16; ++k2) {
            uint4 wv = wCp[k2 * 256];
            float4 h4 = h0v[k2];
            float4 g4 = h1v[k2];
            const __half* wh = (const __half*)&wv;
            a00 = fmaf(__half2float(wh[0]), h4.x, a00);
            a01 = fmaf(__half2float(wh[0]), h4.y, a01);
            a10 = fmaf(__half2float(wh[1]), h4.x, a10);
            a11 = fmaf(__half2float(wh[1]), h4.y, a11);
            a00 = fmaf(__half2float(wh[2]), h4.z, a00);
            a01 = fmaf(__half2float(wh[2]), h4.w, a01);
            a10 = fmaf(__half2float(wh[3]), h4.z, a10);
            a11 = fmaf(__half2float(wh[3]), h4.w, a11);
            a00 = fmaf(__half2float(wh[4]), g4.x, a00);
            a01 = fmaf(__half2float(wh[4]), g4.y, a01);
            a10 = fmaf(__half2float(wh[5]), g4.x, a10);
            a11 = fmaf(__half2float(wh[5]), g4.y, a11);
            a00 = fmaf(__half2float(wh[6]), g4.z, a00);
            a01 = fmaf(__half2float(wh[6]), g4.w, a01);
            a10 = fmaf(__half2float(wh[7]), g4.z, a10);
            a11 = fmaf(__half2float(wh[7]), g4.w, a11);
        }
        gp[(kq * 4 + 0) * 256 + j] = a00;
        gp[(kq * 4 + 1) * 256 + j] = a01;
        gp[(kq * 4 + 2) * 256 + j] = a10;
        gp[(kq * 4 + 3) * 256 + j] = a11;
        __syncthreads();

        // ---------- Phase D: layer-1 state update ----------
        if (tid < 256) {
            float ip = b1s[uk], fp = b1s[128 + uk], gg = b1s[256 + uk], op = b1s[384 + uk];
#pragma unroll
            for (int q = 0; q < 4; ++q) {
                ip += gp[(q * 4 + ur) * 256 + uk];
                fp += gp[(q * 4 + ur) * 256 + 128 + uk];
                gg += gp[(q * 4 + 2 + ur) * 256 + uk];
                op += gp[(q * 4 + 2 + ur) * 256 + 128 + uk];
            }
            c1 = sigf(fp) * c1 + sigf(ip) * tanh_fast(gg);
            hb1[(uk >> 1) * 4 + (uk & 1) * 2 + ur] = sigf(op) * tanh_fast(c1);
        }
        __syncthreads();
    }

    // ---------- head MLP ----------
    if (tid < 128) {
        int r = tid >> 6, m = tid & 63;
        float acc = fp_b1[m];
        const float* wp = fp_w1 + m * HH;
        for (int k = 0; k < HH; ++k)
            acc = fmaf(wp[k], hb1[(k >> 1) * 4 + (k & 1) * 2 + r], acc);
        t1s[r][m] = fmaxf(acc, 0.f);
    }
    __syncthreads();
    if (tid < 64) {
        int r = tid >> 5, q = tid & 31;
        float acc = fp_b2[q];
        const float* wp = fp_w2 + q * 64;
        for (int m = 0; m < 64; ++m) acc = fmaf(wp[m], t1s[r][m], acc);
        bss[r][q] = tanh_fast(acc);
    }
    __syncthreads();
    if (tid < 2) {
        float s = 0.f;
        for (int q = 0; q < 32; ++q) s += bss[tid][q];
        feat_sum[brow + tid] = s;
    }
}

// ---------------------------------------------------------------------------
// K2: neuron activations + group means.  one block per batch row.
// ---------------------------------------------------------------------------
__global__ __launch_bounds__(256) void neuron_kernel(
    const float* __restrict__ feat_sum, const float* __restrict__ a,
    const float* __restrict__ thr,
    float* __restrict__ no, float* __restrict__ means)
{
    const int b = blockIdx.x;
    const float s = feat_sum[b];
    float g0 = 0.f, g1 = 0.f, g2 = 0.f, g3 = 0.f;
    for (int n = threadIdx.x; n < NN; n += 256) {
        float pre = s * a[n];
        float v;
        if (n < O0)        { v = sigf(pre - thr[n]);          g0 += v; }
        else if (n < O1)   { v = tanh_fast(pre);              g1 += v; }
        else if (n < O2)   { v = fmaxf(pre - thr[n], 0.f);    g2 += v; }
        else               { v = sigf(pre);                   g3 += v; }
        no[b * NN + n] = v;
    }
    __shared__ float red[4][256];
    red[0][threadIdx.x] = g0; red[1][threadIdx.x] = g1;
    red[2][threadIdx.x] = g2; red[3][threadIdx.x] = g3;
    __syncthreads();
    if (threadIdx.x < 4) {
        float acc = 0.f;
        for (int i = 0; i < 256; ++i) acc += red[threadIdx.x][i];
        const float inv[4] = {1.f / 800.f, 1.f / 700.f, 1.f / 600.f, 1.f / 400.f};
        means[b * 4 + threadIdx.x] = acc * inv[threadIdx.x];
    }
}

// ---------------------------------------------------------------------------
// K3: h1 = relu(no @ int_w1.T + int_b1)  M=512 N=256 K=2500.
// B loaded directly from int_w1 (transposed into LDS tile) -- no prep transpose.
// ---------------------------------------------------------------------------
__global__ __launch_bounds__(256) void gemm_h1(
    const float* __restrict__ no,
    const float* __restrict__ int_w1,   // 256 x 2500
    const float* __restrict__ int_b1,
    float* __restrict__ h1)
{
    __shared__ float As[32][33];
    __shared__ float Bs[32][33];
    const int b0 = blockIdx.x * 32;
    const int m0 = blockIdx.y * 32;
    const int tid = threadIdx.x;
    const int ty = tid >> 4, tx = tid & 15;
    const int li = tid >> 3;
    const int lj = (tid & 7) * 4;

    float acc00 = 0.f, acc01 = 0.f, acc10 = 0.f, acc11 = 0.f;

    for (int k0 = 0; k0 < NN; k0 += 32) {
        float4 av = make_float4(0.f, 0.f, 0.f, 0.f);
        if (k0 + lj < NN)
            av = *(const float4*)(no + (b0 + li) * NN + k0 + lj);
        As[li][lj + 0] = av.x; As[li][lj + 1] = av.y;
        As[li][lj + 2] = av.z; As[li][lj + 3] = av.w;

        float4 wv = make_float4(0.f, 0.f, 0.f, 0.f);
        if (k0 + lj < NN)
            wv = *(const float4*)(int_w1 + (m0 + li) * NN + k0 + lj);
        Bs[lj + 0][li] = wv.x; Bs[lj + 1][li] = wv.y;
        Bs[lj + 2][li] = wv.z; Bs[lj + 3][li] = wv.w;
        __syncthreads();

#pragma unroll 8
        for (int kk = 0; kk < 32; ++kk) {
            float a0 = As[ty * 2][kk],  a1 = As[ty * 2 + 1][kk];
            float w0 = Bs[kk][tx * 2],  w1 = Bs[kk][tx * 2 + 1];
            acc00 += a0 * w0; acc01 += a0 * w1;
            acc10 += a1 * w0; acc11 += a1 * w1;
        }
        __syncthreads();
    }
    const int bi = b0 + ty * 2, mj = m0 + tx * 2;
    h1[bi * 256 + mj]           = fmaxf(acc00 + int_b1[mj], 0.f);
    h1[bi * 256 + mj + 1]       = fmaxf(acc01 + int_b1[mj + 1], 0.f);
    h1[(bi + 1) * 256 + mj]     = fmaxf(acc10 + int_b1[mj], 0.f);
    h1[(bi + 1) * 256 + mj + 1] = fmaxf(acc11 + int_b1[mj + 1], 0.f);
}

// ---------------------------------------------------------------------------
// K4: tail MLP + output assembly.  one wave per batch row.
// ---------------------------------------------------------------------------
__global__ __launch_bounds__(64) void tail_kernel(
    const float* __restrict__ h1,
    const float* __restrict__ int_w2, const float* __restrict__ int_b2,
    const float* __restrict__ int_w3, const float* __restrict__ int_b3,
    const float* __restrict__ tw, const float* __restrict__ tb,
    const float* __restrict__ pw, const float* __restrict__ pb,
    const float* __restrict__ kw, const float* __restrict__ kb,
    const float* __restrict__ vw, const float* __restrict__ vb,
    const float* __restrict__ cw, const float* __restrict__ cb,
    const float* __restrict__ means,
    float* __restrict__ out)
{
    const int b = blockIdx.x;
    const int lane = threadIdx.x;
    __shared__ float h2s[64];
    __shared__ float ints[32];
    __shared__ float outs[16];

    {
        float acc = int_b2[lane];
        const float* hp = h1 + b * 256;
        const float* wp = int_w2 + lane * 256;
        for (int m = 0; m < 256; ++m) acc += wp[m] * hp[m];
        h2s[lane] = fmaxf(acc, 0.f);
    }
    __syncthreads();
    if (lane < 32) {
        float acc = int_b3[lane];
        const float* wp = int_w3 + lane * 64;
        for (int m = 0; m < 64; ++m) acc += wp[m] * h2s[m];
        ints[lane] = tanh_fast(acc);
    }
    __syncthreads();
    if (lane < 15) {
        const float* wsel; float bsel;
        if (lane < 3)       { wsel = tw + lane * 32;       bsel = tb[lane]; }
        else if (lane < 9)  { wsel = pw + (lane - 3) * 32; bsel = pb[lane - 3]; }
        else if (lane < 13) { wsel = kw + (lane - 9) * 32; bsel = kb[lane - 9]; }
        else if (lane == 13){ wsel = vw;                   bsel = vb[0]; }
        else                { wsel = cw;                   bsel = cb[0]; }
        float acc = bsel;
        for (int q = 0; q < 32; ++q) acc += wsel[q] * ints[q];
        outs[lane] = acc;
    }
    __syncthreads();
    if (lane < 20) {
        float v;
        if (lane < 15)       v = outs[lane];
        else if (lane == 15) v = sigf(outs[14]);
        else                 v = means[b * 4 + (lane - 16)];
        out[b * 20 + lane] = v;
    }
}

// ---------------------------------------------------------------------------
extern "C" void kernel_launch(void* const* d_in, const int* in_sizes, int n_in,
                              void* d_out, int out_size, void* d_ws, size_t ws_size,
                              hipStream_t stream)
{
    const float* x      = (const float*)d_in[0];
    const float* W_ih0  = (const float*)d_in[1];
    const float* W_hh0  = (const float*)d_in[2];
    const float* b_ih0  = (const float*)d_in[3];
    const float* b_hh0  = (const float*)d_in[4];
    const float* W_ih1  = (const float*)d_in[5];
    const float* W_hh1  = (const float*)d_in[6];
    const float* b_ih1  = (const float*)d_in[7];
    const float* b_hh1  = (const float*)d_in[8];
    const float* fp_w1  = (const float*)d_in[9];
    const float* fp_b1  = (const float*)d_in[10];
    const float* fp_w2  = (const float*)d_in[11];
    const float* fp_b2  = (const float*)d_in[12];
    const float* conn_w = (const float*)d_in[13];
    const float* sens   = (const float*)d_in[14];
    const float* thr    = (const float*)d_in[15];
    const float* int_w1 = (const float*)d_in[16];
    const float* int_b1 = (const float*)d_in[17];
    const float* int_w2 = (const float*)d_in[18];
    const float* int_b2 = (const float*)d_in[19];
    const float* int_w3 = (const float*)d_in[20];
    const float* int_b3 = (const float*)d_in[21];
    const float* tw     = (const float*)d_in[22];
    const float* tb     = (const float*)d_in[23];
    const float* pw     = (const float*)d_in[24];
    const float* pb     = (const float*)d_in[25];
    const float* kw     = (const float*)d_in[26];
    const float* kb     = (const float*)d_in[27];
    const float* vw     = (const float*)d_in[28];
    const float* vb     = (const float*)d_in[29];
    const float* cw     = (const float*)d_in[30];
    const float* cb     = (const float*)d_in[31];
    // d_in[32] = conn_idx -- unused: acts is a feat_sum broadcast, so the
    // gather/einsum collapses to feat_sum[b] * rowsum(conn_w)[n].

    float* ws = (float*)d_ws;
    float* out = (float*)d_out;

    prep_kernel<<<(PREP_TOTAL + 255) / 256, 256, 0, stream>>>(
        W_ih0, W_hh0, b_ih0, b_hh0, W_ih1, W_hh1, b_ih1, b_hh1,
        conn_w, sens, ws);

    lstm_fused<<<NB / 2, 1024, 0, stream>>>(
        x, ws, fp_w1, fp_b1, fp_w2, fp_b2, ws + OFF_FS);

    neuron_kernel<<<NB, 256, 0, stream>>>(
        ws + OFF_FS, ws + OFF_A, thr, ws + OFF_NO, ws + OFF_MEANS);

    {
        dim3 grid(NB / 32, 256 / 32);
        gemm_h1<<<grid, 256, 0, stream>>>(
            ws + OFF_NO, int_w1, int_b1, ws + OFF_H1);
    }

    tail_kernel<<<NB, 64, 0, stream>>>(
        ws + OFF_H1, int_w2, int_b2, int_w3, int_b3,
        tw, tb, pw, pb, kw, kb, vw, vb, cw, cb,
        ws + OFF_MEANS, out);
}

// Round 3
// 561.513 us; speedup vs baseline: 4.6654x; 4.6654x over previous
//
#include <hip/hip_runtime.h>
#include <math.h>

// ---------------------------------------------------------------------------
// Sizes
// ---------------------------------------------------------------------------
#define NB   512
#define TT   60
#define FF   5
#define HH   128
#define G4   512
#define NN   2500
#define KK   50

#define O0 800
#define O1 1500
#define O2 2100

// workspace layout (float offsets)
#define OFF_WHH0T 0                    // [k][j] 128*512
#define OFF_WIH1T (OFF_WHH0T + 65536)
#define OFF_WHH1T (OFF_WIH1T + 65536)
#define OFF_W0T   (OFF_WHH1T + 65536)  // [f][j] 5*512
#define OFF_B0    (OFF_W0T + 2560)     // 512
#define OFF_B1    (OFF_B0 + 512)       // 512
#define OFF_A     (OFF_B1 + 512)       // 2500
#define OFF_FS    (OFF_A + 2500)       // 512
#define OFF_NO    (OFF_FS + 512)       // 512*2500
#define OFF_MEANS (OFF_NO + NB*NN)     // 2048
#define OFF_H1    (OFF_MEANS + 2048)   // 512*256

#define PREP_TOTAL 202692              // 3*65536 + 2560 + 512 + 512 + 2500

__device__ __forceinline__ float sigf(float x) {
    return 1.0f / (1.0f + __expf(-x));
}
__device__ __forceinline__ float tanh_fast(float x) {
    float t = __expf(-2.0f * fabsf(x));
    float r = (1.0f - t) / (1.0f + t);
    return copysignf(r, x);
}

// ---------------------------------------------------------------------------
// K0: prep — fp32 transposes (R1 layout: proven L2-resident), bias folds, a[n]
// ---------------------------------------------------------------------------
__global__ __launch_bounds__(256) void prep_kernel(
    const float* __restrict__ W_ih0, const float* __restrict__ W_hh0,
    const float* __restrict__ b_ih0, const float* __restrict__ b_hh0,
    const float* __restrict__ W_ih1, const float* __restrict__ W_hh1,
    const float* __restrict__ b_ih1, const float* __restrict__ b_hh1,
    const float* __restrict__ conn_w, const float* __restrict__ sens,
    float* __restrict__ ws)
{
    int i = blockIdx.x * 256 + threadIdx.x;
    if (i >= PREP_TOTAL) return;

    if (i < 65536) {                       // Whh0T[k][j] = W_hh0[j][k]
        int k = i >> 9, j = i & 511;
        ws[OFF_WHH0T + i] = W_hh0[j * HH + k];
    } else if (i < 131072) {
        int v = i - 65536;
        int k = v >> 9, j = v & 511;
        ws[OFF_WIH1T + v] = W_ih1[j * HH + k];
    } else if (i < 196608) {
        int v = i - 131072;
        int k = v >> 9, j = v & 511;
        ws[OFF_WHH1T + v] = W_hh1[j * HH + k];
    } else if (i < 199168) {               // W0T[f][j] = W_ih0[j][f]
        int v = i - 196608;
        int f = v >> 9, j = v & 511;
        ws[OFF_W0T + v] = W_ih0[j * FF + f];
    } else if (i < 199680) {
        int j = i - 199168;
        ws[OFF_B0 + j] = b_ih0[j] + b_hh0[j];
    } else if (i < 200192) {
        int j = i - 199680;
        ws[OFF_B1 + j] = b_ih1[j] + b_hh1[j];
    } else {
        int n = i - 200192;
        float s = 0.f;
        const float* cw = conn_w + n * KK;
        for (int k = 0; k < KK; ++k) s += cw[k];
        ws[OFF_A + n] = s * sens[n];
    }
}

// ---------------------------------------------------------------------------
// K1: fused 2-layer LSTM + feature head.
// 256 blocks x 1024 threads, 2 batch rows/block.
// j = tid&511 (gate column), half = tid>>9 (wave-uniform work split):
//   layer 0: half 0 -> k in [0,64) (+ x@W0T), half 1 -> k in [64,128)
//   layer 1: half 0 -> Wih1 @ h0,              half 1 -> Whh1 @ h1
// Partials meet in gp[2][512] float2; update threads (tid<256) own (row,k) state.
// Weights fp32 [k][j]: lane-coalesced 256B/wave, h via LDS float2 broadcast.
// ---------------------------------------------------------------------------
__global__ __launch_bounds__(1024) void lstm_fused(
    const float* __restrict__ x,
    const float* __restrict__ ws_ro,
    const float* __restrict__ fp_w1, const float* __restrict__ fp_b1,
    const float* __restrict__ fp_w2, const float* __restrict__ fp_b2,
    float* __restrict__ feat_sum)
{
    __shared__ float xs[2][TT * FF + 4];
    __shared__ __align__(16) float hb0[2 * HH];   // [k][r]
    __shared__ __align__(16) float hb1[2 * HH];
    __shared__ float gp[2 * G4 * 2];              // [half][j] float2 (r0,r1)
    __shared__ float t1s[2][64];
    __shared__ float bss[2][32];

    const int tid = threadIdx.x;
    const int j = tid & 511;
    const int half = tid >> 9;
    const int brow = blockIdx.x * 2;

    for (int i = tid; i < 2 * TT * FF; i += 1024) {
        int r = i / (TT * FF), c = i % (TT * FF);
        xs[r][c] = x[(brow + r) * (TT * FF) + c];
    }
    if (tid < 2 * HH) { hb0[tid] = 0.f; hb1[tid] = 0.f; }

    // per-thread weight/bias registers
    float w0r[FF];
    if (half == 0) {
#pragma unroll
        for (int f = 0; f < FF; ++f) w0r[f] = ws_ro[OFF_W0T + f * G4 + j];
    }
    const int ur = (tid >> 7) & 1, uk = tid & 127;
    float bi0 = 0.f, bf0 = 0.f, bg0 = 0.f, bo0 = 0.f;
    float bi1 = 0.f, bf1 = 0.f, bg1 = 0.f, bo1 = 0.f;
    if (tid < 256) {
        bi0 = ws_ro[OFF_B0 + uk];        bf0 = ws_ro[OFF_B0 + 128 + uk];
        bg0 = ws_ro[OFF_B0 + 256 + uk];  bo0 = ws_ro[OFF_B0 + 384 + uk];
        bi1 = ws_ro[OFF_B1 + uk];        bf1 = ws_ro[OFF_B1 + 128 + uk];
        bg1 = ws_ro[OFF_B1 + 256 + uk];  bo1 = ws_ro[OFF_B1 + 384 + uk];
    }
    float c0 = 0.f, c1 = 0.f;

    const float* wA  = ws_ro + OFF_WHH0T + (half << 6) * G4 + j;  // k-half of Whh0
    const float* wC  = (half ? ws_ro + OFF_WHH1T : ws_ro + OFF_WIH1T) + j;
    const float2* h0v = (const float2*)hb0;
    const float2* h1v = (const float2*)hb1;
    const float2* h0half = h0v + (half << 6);
    const float2* hCv = half ? h1v : h0v;
    float2* gpv = (float2*)gp;

    __syncthreads();

    for (int t = 0; t < TT; ++t) {
        // ---------- Phase A: layer-0 partial gates ----------
        float a0 = 0.f, a1 = 0.f;
#pragma unroll 8
        for (int k = 0; k < 64; ++k) {
            float w = wA[k * G4];
            float2 h2 = h0half[k];
            a0 = fmaf(w, h2.x, a0);
            a1 = fmaf(w, h2.y, a1);
        }
        if (half == 0) {
            const float* xr0 = &xs[0][t * FF];
            const float* xr1 = &xs[1][t * FF];
#pragma unroll
            for (int f = 0; f < FF; ++f) {
                a0 = fmaf(w0r[f], xr0[f], a0);
                a1 = fmaf(w0r[f], xr1[f], a1);
            }
        }
        gpv[half * G4 + j] = make_float2(a0, a1);
        __syncthreads();

        // ---------- Phase B: layer-0 state update ----------
        if (tid < 256) {
            float ip = bi0 + gp[(uk) * 2 + ur]             + gp[(G4 + uk) * 2 + ur];
            float fp = bf0 + gp[(128 + uk) * 2 + ur]       + gp[(G4 + 128 + uk) * 2 + ur];
            float gg = bg0 + gp[(256 + uk) * 2 + ur]       + gp[(G4 + 256 + uk) * 2 + ur];
            float op = bo0 + gp[(384 + uk) * 2 + ur]       + gp[(G4 + 384 + uk) * 2 + ur];
            c0 = sigf(fp) * c0 + sigf(ip) * tanh_fast(gg);
            hb0[uk * 2 + ur] = sigf(op) * tanh_fast(c0);
        }
        __syncthreads();

        // ---------- Phase C: layer-1 partial gates ----------
        a0 = 0.f; a1 = 0.f;
#pragma unroll 8
        for (int k = 0; k < HH; ++k) {
            float w = wC[k * G4];
            float2 h2 = hCv[k];
            a0 = fmaf(w, h2.x, a0);
            a1 = fmaf(w, h2.y, a1);
        }
        gpv[half * G4 + j] = make_float2(a0, a1);
        __syncthreads();

        // ---------- Phase D: layer-1 state update ----------
        if (tid < 256) {
            float ip = bi1 + gp[(uk) * 2 + ur]             + gp[(G4 + uk) * 2 + ur];
            float fp = bf1 + gp[(128 + uk) * 2 + ur]       + gp[(G4 + 128 + uk) * 2 + ur];
            float gg = bg1 + gp[(256 + uk) * 2 + ur]       + gp[(G4 + 256 + uk) * 2 + ur];
            float op = bo1 + gp[(384 + uk) * 2 + ur]       + gp[(G4 + 384 + uk) * 2 + ur];
            c1 = sigf(fp) * c1 + sigf(ip) * tanh_fast(gg);
            hb1[uk * 2 + ur] = sigf(op) * tanh_fast(c1);
        }
        __syncthreads();
    }

    // ---------- head MLP ----------
    if (tid < 128) {
        int r = tid >> 6, m = tid & 63;
        float acc = fp_b1[m];
        const float* wp = fp_w1 + m * HH;
        for (int k = 0; k < HH; ++k)
            acc = fmaf(wp[k], hb1[k * 2 + r], acc);
        t1s[r][m] = fmaxf(acc, 0.f);
    }
    __syncthreads();
    if (tid < 64) {
        int r = tid >> 5, q = tid & 31;
        float acc = fp_b2[q];
        const float* wp = fp_w2 + q * 64;
        for (int m = 0; m < 64; ++m) acc = fmaf(wp[m], t1s[r][m], acc);
        bss[r][q] = tanh_fast(acc);
    }
    __syncthreads();
    if (tid < 2) {
        float s = 0.f;
        for (int q = 0; q < 32; ++q) s += bss[tid][q];
        feat_sum[brow + tid] = s;
    }
}

// ---------------------------------------------------------------------------
// K2: neuron activations + group means.  one block per batch row.
// ---------------------------------------------------------------------------
__global__ __launch_bounds__(256) void neuron_kernel(
    const float* __restrict__ feat_sum, const float* __restrict__ a,
    const float* __restrict__ thr,
    float* __restrict__ no, float* __restrict__ means)
{
    const int b = blockIdx.x;
    const float s = feat_sum[b];
    float g0 = 0.f, g1 = 0.f, g2 = 0.f, g3 = 0.f;
    for (int n = threadIdx.x; n < NN; n += 256) {
        float pre = s * a[n];
        float v;
        if (n < O0)        { v = sigf(pre - thr[n]);          g0 += v; }
        else if (n < O1)   { v = tanh_fast(pre);              g1 += v; }
        else if (n < O2)   { v = fmaxf(pre - thr[n], 0.f);    g2 += v; }
        else               { v = sigf(pre);                   g3 += v; }
        no[b * NN + n] = v;
    }
    __shared__ float red[4][256];
    red[0][threadIdx.x] = g0; red[1][threadIdx.x] = g1;
    red[2][threadIdx.x] = g2; red[3][threadIdx.x] = g3;
    __syncthreads();
    if (threadIdx.x < 4) {
        float acc = 0.f;
        for (int i = 0; i < 256; ++i) acc += red[threadIdx.x][i];
        const float inv[4] = {1.f / 800.f, 1.f / 700.f, 1.f / 600.f, 1.f / 400.f};
        means[b * 4 + threadIdx.x] = acc * inv[threadIdx.x];
    }
}

// ---------------------------------------------------------------------------
// K3: h1 = relu(no @ int_w1.T + int_b1)  M=512 N=256 K=2500
// ---------------------------------------------------------------------------
__global__ __launch_bounds__(256) void gemm_h1(
    const float* __restrict__ no,
    const float* __restrict__ int_w1,   // 256 x 2500
    const float* __restrict__ int_b1,
    float* __restrict__ h1)
{
    __shared__ float As[32][33];
    __shared__ float Bs[32][33];
    const int b0 = blockIdx.x * 32;
    const int m0 = blockIdx.y * 32;
    const int tid = threadIdx.x;
    const int ty = tid >> 4, tx = tid & 15;
    const int li = tid >> 3;
    const int lj = (tid & 7) * 4;

    float acc00 = 0.f, acc01 = 0.f, acc10 = 0.f, acc11 = 0.f;

    for (int k0 = 0; k0 < NN; k0 += 32) {
        float4 av = make_float4(0.f, 0.f, 0.f, 0.f);
        if (k0 + lj < NN)
            av = *(const float4*)(no + (b0 + li) * NN + k0 + lj);
        As[li][lj + 0] = av.x; As[li][lj + 1] = av.y;
        As[li][lj + 2] = av.z; As[li][lj + 3] = av.w;

        float4 wv = make_float4(0.f, 0.f, 0.f, 0.f);
        if (k0 + lj < NN)
            wv = *(const float4*)(int_w1 + (m0 + li) * NN + k0 + lj);
        Bs[lj + 0][li] = wv.x; Bs[lj + 1][li] = wv.y;
        Bs[lj + 2][li] = wv.z; Bs[lj + 3][li] = wv.w;
        __syncthreads();

#pragma unroll 8
        for (int kk = 0; kk < 32; ++kk) {
            float a0 = As[ty * 2][kk],  a1 = As[ty * 2 + 1][kk];
            float w0 = Bs[kk][tx * 2],  w1 = Bs[kk][tx * 2 + 1];
            acc00 += a0 * w0; acc01 += a0 * w1;
            acc10 += a1 * w0; acc11 += a1 * w1;
        }
        __syncthreads();
    }
    const int bi = b0 + ty * 2, mj = m0 + tx * 2;
    h1[bi * 256 + mj]           = fmaxf(acc00 + int_b1[mj], 0.f);
    h1[bi * 256 + mj + 1]       = fmaxf(acc01 + int_b1[mj + 1], 0.f);
    h1[(bi + 1) * 256 + mj]     = fmaxf(acc10 + int_b1[mj], 0.f);
    h1[(bi + 1) * 256 + mj + 1] = fmaxf(acc11 + int_b1[mj + 1], 0.f);
}

// ---------------------------------------------------------------------------
// K4: tail MLP + output assembly.  one wave per batch row.
// ---------------------------------------------------------------------------
__global__ __launch_bounds__(64) void tail_kernel(
    const float* __restrict__ h1,
    const float* __restrict__ int_w2, const float* __restrict__ int_b2,
    const float* __restrict__ int_w3, const float* __restrict__ int_b3,
    const float* __restrict__ tw, const float* __restrict__ tb,
    const float* __restrict__ pw, const float* __restrict__ pb,
    const float* __restrict__ kw, const float* __restrict__ kb,
    const float* __restrict__ vw, const float* __restrict__ vb,
    const float* __restrict__ cw, const float* __restrict__ cb,
    const float* __restrict__ means,
    float* __restrict__ out)
{
    const int b = blockIdx.x;
    const int lane = threadIdx.x;
    __shared__ float h2s[64];
    __shared__ float ints[32];
    __shared__ float outs[16];

    {
        float acc = int_b2[lane];
        const float* hp = h1 + b * 256;
        const float* wp = int_w2 + lane * 256;
        for (int m = 0; m < 256; ++m) acc += wp[m] * hp[m];
        h2s[lane] = fmaxf(acc, 0.f);
    }
    __syncthreads();
    if (lane < 32) {
        float acc = int_b3[lane];
        const float* wp = int_w3 + lane * 64;
        for (int m = 0; m < 64; ++m) acc += wp[m] * h2s[m];
        ints[lane] = tanh_fast(acc);
    }
    __syncthreads();
    if (lane < 15) {
        const float* wsel; float bsel;
        if (lane < 3)       { wsel = tw + lane * 32;       bsel = tb[lane]; }
        else if (lane < 9)  { wsel = pw + (lane - 3) * 32; bsel = pb[lane - 3]; }
        else if (lane < 13) { wsel = kw + (lane - 9) * 32; bsel = kb[lane - 9]; }
        else if (lane == 13){ wsel = vw;                   bsel = vb[0]; }
        else                { wsel = cw;                   bsel = cb[0]; }
        float acc = bsel;
        for (int q = 0; q < 32; ++q) acc += wsel[q] * ints[q];
        outs[lane] = acc;
    }
    __syncthreads();
    if (lane < 20) {
        float v;
        if (lane < 15)       v = outs[lane];
        else if (lane == 15) v = sigf(outs[14]);
        else                 v = means[b * 4 + (lane - 16)];
        out[b * 20 + lane] = v;
    }
}

// ---------------------------------------------------------------------------
extern "C" void kernel_launch(void* const* d_in, const int* in_sizes, int n_in,
                              void* d_out, int out_size, void* d_ws, size_t ws_size,
                              hipStream_t stream)
{
    const float* x      = (const float*)d_in[0];
    const float* W_ih0  = (const float*)d_in[1];
    const float* W_hh0  = (const float*)d_in[2];
    const float* b_ih0  = (const float*)d_in[3];
    const float* b_hh0  = (const float*)d_in[4];
    const float* W_ih1  = (const float*)d_in[5];
    const float* W_hh1  = (const float*)d_in[6];
    const float* b_ih1  = (const float*)d_in[7];
    const float* b_hh1  = (const float*)d_in[8];
    const float* fp_w1  = (const float*)d_in[9];
    const float* fp_b1  = (const float*)d_in[10];
    const float* fp_w2  = (const float*)d_in[11];
    const float* fp_b2  = (const float*)d_in[12];
    const float* conn_w = (const float*)d_in[13];
    const float* sens   = (const float*)d_in[14];
    const float* thr    = (const float*)d_in[15];
    const float* int_w1 = (const float*)d_in[16];
    const float* int_b1 = (const float*)d_in[17];
    const float* int_w2 = (const float*)d_in[18];
    const float* int_b2 = (const float*)d_in[19];
    const float* int_w3 = (const float*)d_in[20];
    const float* int_b3 = (const float*)d_in[21];
    const float* tw     = (const float*)d_in[22];
    const float* tb     = (const float*)d_in[23];
    const float* pw     = (const float*)d_in[24];
    const float* pb     = (const float*)d_in[25];
    const float* kw     = (const float*)d_in[26];
    const float* kb     = (const float*)d_in[27];
    const float* vw     = (const float*)d_in[28];
    const float* vb     = (const float*)d_in[29];
    const float* cw     = (const float*)d_in[30];
    const float* cb     = (const float*)d_in[31];
    // d_in[32] = conn_idx -- unused: acts is a feat_sum broadcast, so the
    // gather/einsum collapses to feat_sum[b] * rowsum(conn_w)[n].

    float* ws = (float*)d_ws;
    float* out = (float*)d_out;

    prep_kernel<<<(PREP_TOTAL + 255) / 256, 256, 0, stream>>>(
        W_ih0, W_hh0, b_ih0, b_hh0, W_ih1, W_hh1, b_ih1, b_hh1,
        conn_w, sens, ws);

    lstm_fused<<<NB / 2, 1024, 0, stream>>>(
        x, ws, fp_w1, fp_b1, fp_w2, fp_b2, ws + OFF_FS);

    neuron_kernel<<<NB, 256, 0, stream>>>(
        ws + OFF_FS, ws + OFF_A, thr, ws + OFF_NO, ws + OFF_MEANS);

    {
        dim3 grid(NB / 32, 256 / 32);
        gemm_h1<<<grid, 256, 0, stream>>>(
            ws + OFF_NO, int_w1, int_b1, ws + OFF_H1);
    }

    tail_kernel<<<NB, 64, 0, stream>>>(
        ws + OFF_H1, int_w2, int_b2, int_w3, int_b3,
        tw, tb, pw, pb, kw, kb, vw, vb, cw, cb,
        ws + OFF_MEANS, out);
}

// Round 4
// 380.948 us; speedup vs baseline: 6.8768x; 1.4740x over previous
//
#include <hip/hip_runtime.h>
#include <math.h>

// ---------------------------------------------------------------------------
// Sizes
// ---------------------------------------------------------------------------
#define NB   512
#define TT   60
#define FF   5
#define HH   128
#define G4   512
#define NN   2500
#define KK   50

#define O0 800
#define O1 1500
#define O2 2100

// workspace layout (float offsets)
// fp16 weight arrays: 65536 halves = 32768 floats each.
// packed layout: halfidx = k2*1024 + j*2 + kk  (k = 2*k2+kk), value = W[j][k]
#define OFF_WA    0                    // W_hh0 fp16
#define OFF_WB    32768                // W_ih1 fp16
#define OFF_WC    65536                // W_hh1 fp16
#define OFF_W0T   98304                // [f][j] 5*512 fp32
#define OFF_B0    100864               // 512
#define OFF_B1    101376               // 512
#define OFF_A     101888               // 2500
#define OFF_FS    104388               // 512
#define OFF_NO    104900               // 512*2500
#define OFF_MEANS (OFF_NO + NB*NN)     // 2048
#define OFF_H1    (OFF_MEANS + 2048)   // 512*256

#define PREP_TOTAL 202692              // 3*65536 + 2560 + 512 + 512 + 2500

typedef _Float16 half2v __attribute__((ext_vector_type(2)));

#if defined(__has_builtin)
#if __has_builtin(__builtin_amdgcn_fdot2)
#define DOT2(a, b, c) __builtin_amdgcn_fdot2((a), (b), (c), false)
#endif
#endif
#ifndef DOT2
#define DOT2(a, b, c) fmaf((float)(a).x, (float)(b).x, fmaf((float)(a).y, (float)(b).y, (c)))
#endif

union WU { unsigned u; half2v h; };
union HU { uint2 u2; half2v h[2]; };

__device__ __forceinline__ float sigf(float x) {
    return 1.0f / (1.0f + __expf(-x));
}
__device__ __forceinline__ float tanh_fast(float x) {
    float t = __expf(-2.0f * fabsf(x));
    float r = (1.0f - t) / (1.0f + t);
    return copysignf(r, x);
}

// ---------------------------------------------------------------------------
// K0: prep — fp16 packed weight transposes, bias folds, a[n]
// ---------------------------------------------------------------------------
__global__ __launch_bounds__(256) void prep_kernel(
    const float* __restrict__ W_ih0, const float* __restrict__ W_hh0,
    const float* __restrict__ b_ih0, const float* __restrict__ b_hh0,
    const float* __restrict__ W_ih1, const float* __restrict__ W_hh1,
    const float* __restrict__ b_ih1, const float* __restrict__ b_hh1,
    const float* __restrict__ conn_w, const float* __restrict__ sens,
    float* __restrict__ ws)
{
    int i = blockIdx.x * 256 + threadIdx.x;
    if (i >= PREP_TOTAL) return;

    if (i < 196608) {                      // three fp16 weight arrays
        int m = i >> 16;                   // 0:Whh0 1:Wih1 2:Whh1
        int v = i & 65535;
        int k2 = v >> 10, rem = v & 1023, j = rem >> 1, kk = rem & 1;
        const float* src = (m == 0) ? W_hh0 : (m == 1) ? W_ih1 : W_hh1;
        _Float16* dst = (_Float16*)(ws + (m == 0 ? OFF_WA : m == 1 ? OFF_WB : OFF_WC));
        dst[v] = (_Float16)src[j * HH + (k2 * 2 + kk)];
    } else if (i < 199168) {               // W0T[f][j] = W_ih0[j][f]
        int v = i - 196608;
        int f = v >> 9, j = v & 511;
        ws[OFF_W0T + v] = W_ih0[j * FF + f];
    } else if (i < 199680) {
        int j = i - 199168;
        ws[OFF_B0 + j] = b_ih0[j] + b_hh0[j];
    } else if (i < 200192) {
        int j = i - 199680;
        ws[OFF_B1 + j] = b_ih1[j] + b_hh1[j];
    } else {
        int n = i - 200192;
        float s = 0.f;
        const float* cw = conn_w + n * KK;
        for (int k = 0; k < KK; ++k) s += cw[k];
        ws[OFF_A + n] = s * sens[n];
    }
}

// ---------------------------------------------------------------------------
// K1: fused 2-layer LSTM + feature head.
// 256 blocks x 1024 threads, 2 rows/block (R3 skeleton).
// fp16 weights (2 k's per dword), fp16 h packed [k2]{r0 pair, r1 pair} uint2,
// v_dot2_f32_f16 accumulate in fp32.
//   layer 0: half 0 -> k2 in [0,32) (+ x@W0T), half 1 -> k2 in [32,64)
//   layer 1: half 0 -> Wih1 @ h0,              half 1 -> Whh1 @ h1
// ---------------------------------------------------------------------------
__global__ __launch_bounds__(1024) void lstm_fused(
    const float* __restrict__ x,
    const float* __restrict__ ws_ro,
    const float* __restrict__ fp_w1, const float* __restrict__ fp_b1,
    const float* __restrict__ fp_w2, const float* __restrict__ fp_b2,
    float* __restrict__ feat_sum)
{
    __shared__ float xs[2][TT * FF + 4];
    __shared__ uint2 hb0h[HH / 2];                // [k2] {r0:half2(k,k+1), r1:half2}
    __shared__ uint2 hb1h[HH / 2];
    __shared__ float gp[2 * G4 * 2];              // [half][j] float2 (r0,r1)
    __shared__ float t1s[2][64];
    __shared__ float bss[2][32];

    const int tid = threadIdx.x;
    const int j = tid & 511;
    const int half = tid >> 9;
    const int brow = blockIdx.x * 2;

    for (int i = tid; i < 2 * TT * FF; i += 1024) {
        int r = i / (TT * FF), c = i % (TT * FF);
        xs[r][c] = x[(brow + r) * (TT * FF) + c];
    }
    if (tid < HH / 2) { hb0h[tid] = make_uint2(0u, 0u); hb1h[tid] = make_uint2(0u, 0u); }

    float w0r[FF];
    if (half == 0) {
#pragma unroll
        for (int f = 0; f < FF; ++f) w0r[f] = ws_ro[OFF_W0T + f * G4 + j];
    }
    const int ur = (tid >> 7) & 1, uk = tid & 127;
    float bi0 = 0.f, bf0 = 0.f, bg0 = 0.f, bo0 = 0.f;
    float bi1 = 0.f, bf1 = 0.f, bg1 = 0.f, bo1 = 0.f;
    if (tid < 256) {
        bi0 = ws_ro[OFF_B0 + uk];        bf0 = ws_ro[OFF_B0 + 128 + uk];
        bg0 = ws_ro[OFF_B0 + 256 + uk];  bo0 = ws_ro[OFF_B0 + 384 + uk];
        bi1 = ws_ro[OFF_B1 + uk];        bf1 = ws_ro[OFF_B1 + 128 + uk];
        bg1 = ws_ro[OFF_B1 + 256 + uk];  bo1 = ws_ro[OFF_B1 + 384 + uk];
    }
    float c0 = 0.f, c1 = 0.f;
    // h write slot for update threads: halfidx = k2*4 + r*2 + kk
    const int hwidx = (uk >> 1) * 4 + ur * 2 + (uk & 1);

    const unsigned* wAp = (const unsigned*)(ws_ro + OFF_WA) + (half << 5) * G4 + j;
    const unsigned* wCp = (const unsigned*)(ws_ro + (half ? OFF_WC : OFF_WB)) + j;
    const uint2* hCs = half ? hb1h : hb0h;
    float2* gpv = (float2*)gp;

    __syncthreads();

    for (int t = 0; t < TT; ++t) {
        // ---------- Phase A: layer-0 partial gates ----------
        float a0 = 0.f, a1 = 0.f;
#pragma unroll 8
        for (int k2 = 0; k2 < 32; ++k2) {
            WU w; w.u = wAp[k2 * G4];
            HU h; h.u2 = hb0h[(half << 5) + k2];
            a0 = DOT2(w.h, h.h[0], a0);
            a1 = DOT2(w.h, h.h[1], a1);
        }
        if (half == 0) {
            const float* xr0 = &xs[0][t * FF];
            const float* xr1 = &xs[1][t * FF];
#pragma unroll
            for (int f = 0; f < FF; ++f) {
                a0 = fmaf(w0r[f], xr0[f], a0);
                a1 = fmaf(w0r[f], xr1[f], a1);
            }
        }
        gpv[half * G4 + j] = make_float2(a0, a1);
        __syncthreads();

        // ---------- Phase B: layer-0 state update ----------
        if (tid < 256) {
            float ip = bi0 + gp[(uk) * 2 + ur]       + gp[(G4 + uk) * 2 + ur];
            float fp = bf0 + gp[(128 + uk) * 2 + ur] + gp[(G4 + 128 + uk) * 2 + ur];
            float gg = bg0 + gp[(256 + uk) * 2 + ur] + gp[(G4 + 256 + uk) * 2 + ur];
            float op = bo0 + gp[(384 + uk) * 2 + ur] + gp[(G4 + 384 + uk) * 2 + ur];
            c0 = sigf(fp) * c0 + sigf(ip) * tanh_fast(gg);
            ((_Float16*)hb0h)[hwidx] = (_Float16)(sigf(op) * tanh_fast(c0));
        }
        __syncthreads();

        // ---------- Phase C: layer-1 partial gates ----------
        a0 = 0.f; a1 = 0.f;
#pragma unroll 8
        for (int k2 = 0; k2 < 64; ++k2) {
            WU w; w.u = wCp[k2 * G4];
            HU h; h.u2 = hCs[k2];
            a0 = DOT2(w.h, h.h[0], a0);
            a1 = DOT2(w.h, h.h[1], a1);
        }
        gpv[half * G4 + j] = make_float2(a0, a1);
        __syncthreads();

        // ---------- Phase D: layer-1 state update ----------
        if (tid < 256) {
            float ip = bi1 + gp[(uk) * 2 + ur]       + gp[(G4 + uk) * 2 + ur];
            float fp = bf1 + gp[(128 + uk) * 2 + ur] + gp[(G4 + 128 + uk) * 2 + ur];
            float gg = bg1 + gp[(256 + uk) * 2 + ur] + gp[(G4 + 256 + uk) * 2 + ur];
            float op = bo1 + gp[(384 + uk) * 2 + ur] + gp[(G4 + 384 + uk) * 2 + ur];
            c1 = sigf(fp) * c1 + sigf(ip) * tanh_fast(gg);
            ((_Float16*)hb1h)[hwidx] = (_Float16)(sigf(op) * tanh_fast(c1));
        }
        __syncthreads();
    }

    // ---------- head MLP ----------
    if (tid < 128) {
        int r = tid >> 6, m = tid & 63;
        float acc = fp_b1[m];
        const float* wp = fp_w1 + m * HH;
        const _Float16* h1h = (const _Float16*)hb1h;
        for (int k = 0; k < HH; ++k)
            acc = fmaf(wp[k], (float)h1h[(k >> 1) * 4 + r * 2 + (k & 1)], acc);
        t1s[r][m] = fmaxf(acc, 0.f);
    }
    __syncthreads();
    if (tid < 64) {
        int r = tid >> 5, q = tid & 31;
        float acc = fp_b2[q];
        const float* wp = fp_w2 + q * 64;
        for (int m = 0; m < 64; ++m) acc = fmaf(wp[m], t1s[r][m], acc);
        bss[r][q] = tanh_fast(acc);
    }
    __syncthreads();
    if (tid < 2) {
        float s = 0.f;
        for (int q = 0; q < 32; ++q) s += bss[tid][q];
        feat_sum[brow + tid] = s;
    }
}

// ---------------------------------------------------------------------------
// K2: neuron activations + group means.  one block per batch row.
// ---------------------------------------------------------------------------
__global__ __launch_bounds__(256) void neuron_kernel(
    const float* __restrict__ feat_sum, const float* __restrict__ a,
    const float* __restrict__ thr,
    float* __restrict__ no, float* __restrict__ means)
{
    const int b = blockIdx.x;
    const float s = feat_sum[b];
    float g0 = 0.f, g1 = 0.f, g2 = 0.f, g3 = 0.f;
    for (int n = threadIdx.x; n < NN; n += 256) {
        float pre = s * a[n];
        float v;
        if (n < O0)        { v = sigf(pre - thr[n]);          g0 += v; }
        else if (n < O1)   { v = tanh_fast(pre);              g1 += v; }
        else if (n < O2)   { v = fmaxf(pre - thr[n], 0.f);    g2 += v; }
        else               { v = sigf(pre);                   g3 += v; }
        no[b * NN + n] = v;
    }
    __shared__ float red[4][256];
    red[0][threadIdx.x] = g0; red[1][threadIdx.x] = g1;
    red[2][threadIdx.x] = g2; red[3][threadIdx.x] = g3;
    __syncthreads();
    if (threadIdx.x < 4) {
        float acc = 0.f;
        for (int i = 0; i < 256; ++i) acc += red[threadIdx.x][i];
        const float inv[4] = {1.f / 800.f, 1.f / 700.f, 1.f / 600.f, 1.f / 400.f};
        means[b * 4 + threadIdx.x] = acc * inv[threadIdx.x];
    }
}

// ---------------------------------------------------------------------------
// K3: h1 = relu(no @ int_w1.T + int_b1)  M=512 N=256 K=2500
// ---------------------------------------------------------------------------
__global__ __launch_bounds__(256) void gemm_h1(
    const float* __restrict__ no,
    const float* __restrict__ int_w1,   // 256 x 2500
    const float* __restrict__ int_b1,
    float* __restrict__ h1)
{
    __shared__ float As[32][33];
    __shared__ float Bs[32][33];
    const int b0 = blockIdx.x * 32;
    const int m0 = blockIdx.y * 32;
    const int tid = threadIdx.x;
    const int ty = tid >> 4, tx = tid & 15;
    const int li = tid >> 3;
    const int lj = (tid & 7) * 4;

    float acc00 = 0.f, acc01 = 0.f, acc10 = 0.f, acc11 = 0.f;

    for (int k0 = 0; k0 < NN; k0 += 32) {
        float4 av = make_float4(0.f, 0.f, 0.f, 0.f);
        if (k0 + lj < NN)
            av = *(const float4*)(no + (b0 + li) * NN + k0 + lj);
        As[li][lj + 0] = av.x; As[li][lj + 1] = av.y;
        As[li][lj + 2] = av.z; As[li][lj + 3] = av.w;

        float4 wv = make_float4(0.f, 0.f, 0.f, 0.f);
        if (k0 + lj < NN)
            wv = *(const float4*)(int_w1 + (m0 + li) * NN + k0 + lj);
        Bs[lj + 0][li] = wv.x; Bs[lj + 1][li] = wv.y;
        Bs[lj + 2][li] = wv.z; Bs[lj + 3][li] = wv.w;
        __syncthreads();

#pragma unroll 8
        for (int kk = 0; kk < 32; ++kk) {
            float a0 = As[ty * 2][kk],  a1 = As[ty * 2 + 1][kk];
            float w0 = Bs[kk][tx * 2],  w1 = Bs[kk][tx * 2 + 1];
            acc00 += a0 * w0; acc01 += a0 * w1;
            acc10 += a1 * w0; acc11 += a1 * w1;
        }
        __syncthreads();
    }
    const int bi = b0 + ty * 2, mj = m0 + tx * 2;
    h1[bi * 256 + mj]           = fmaxf(acc00 + int_b1[mj], 0.f);
    h1[bi * 256 + mj + 1]       = fmaxf(acc01 + int_b1[mj + 1], 0.f);
    h1[(bi + 1) * 256 + mj]     = fmaxf(acc10 + int_b1[mj], 0.f);
    h1[(bi + 1) * 256 + mj + 1] = fmaxf(acc11 + int_b1[mj + 1], 0.f);
}

// ---------------------------------------------------------------------------
// K4: tail MLP + output assembly.  one wave per batch row.
// ---------------------------------------------------------------------------
__global__ __launch_bounds__(64) void tail_kernel(
    const float* __restrict__ h1,
    const float* __restrict__ int_w2, const float* __restrict__ int_b2,
    const float* __restrict__ int_w3, const float* __restrict__ int_b3,
    const float* __restrict__ tw, const float* __restrict__ tb,
    const float* __restrict__ pw, const float* __restrict__ pb,
    const float* __restrict__ kw, const float* __restrict__ kb,
    const float* __restrict__ vw, const float* __restrict__ vb,
    const float* __restrict__ cw, const float* __restrict__ cb,
    const float* __restrict__ means,
    float* __restrict__ out)
{
    const int b = blockIdx.x;
    const int lane = threadIdx.x;
    __shared__ float h2s[64];
    __shared__ float ints[32];
    __shared__ float outs[16];

    {
        float acc = int_b2[lane];
        const float* hp = h1 + b * 256;
        const float* wp = int_w2 + lane * 256;
        for (int m = 0; m < 256; ++m) acc += wp[m] * hp[m];
        h2s[lane] = fmaxf(acc, 0.f);
    }
    __syncthreads();
    if (lane < 32) {
        float acc = int_b3[lane];
        const float* wp = int_w3 + lane * 64;
        for (int m = 0; m < 64; ++m) acc += wp[m] * h2s[m];
        ints[lane] = tanh_fast(acc);
    }
    __syncthreads();
    if (lane < 15) {
        const float* wsel; float bsel;
        if (lane < 3)       { wsel = tw + lane * 32;       bsel = tb[lane]; }
        else if (lane < 9)  { wsel = pw + (lane - 3) * 32; bsel = pb[lane - 3]; }
        else if (lane < 13) { wsel = kw + (lane - 9) * 32; bsel = kb[lane - 9]; }
        else if (lane == 13){ wsel = vw;                   bsel = vb[0]; }
        else                { wsel = cw;                   bsel = cb[0]; }
        float acc = bsel;
        for (int q = 0; q < 32; ++q) acc += wsel[q] * ints[q];
        outs[lane] = acc;
    }
    __syncthreads();
    if (lane < 20) {
        float v;
        if (lane < 15)       v = outs[lane];
        else if (lane == 15) v = sigf(outs[14]);
        else                 v = means[b * 4 + (lane - 16)];
        out[b * 20 + lane] = v;
    }
}

// ---------------------------------------------------------------------------
extern "C" void kernel_launch(void* const* d_in, const int* in_sizes, int n_in,
                              void* d_out, int out_size, void* d_ws, size_t ws_size,
                              hipStream_t stream)
{
    const float* x      = (const float*)d_in[0];
    const float* W_ih0  = (const float*)d_in[1];
    const float* W_hh0  = (const float*)d_in[2];
    const float* b_ih0  = (const float*)d_in[3];
    const float* b_hh0  = (const float*)d_in[4];
    const float* W_ih1  = (const float*)d_in[5];
    const float* W_hh1  = (const float*)d_in[6];
    const float* b_ih1  = (const float*)d_in[7];
    const float* b_hh1  = (const float*)d_in[8];
    const float* fp_w1  = (const float*)d_in[9];
    const float* fp_b1  = (const float*)d_in[10];
    const float* fp_w2  = (const float*)d_in[11];
    const float* fp_b2  = (const float*)d_in[12];
    const float* conn_w = (const float*)d_in[13];
    const float* sens   = (const float*)d_in[14];
    const float* thr    = (const float*)d_in[15];
    const float* int_w1 = (const float*)d_in[16];
    const float* int_b1 = (const float*)d_in[17];
    const float* int_w2 = (const float*)d_in[18];
    const float* int_b2 = (const float*)d_in[19];
    const float* int_w3 = (const float*)d_in[20];
    const float* int_b3 = (const float*)d_in[21];
    const float* tw     = (const float*)d_in[22];
    const float* tb     = (const float*)d_in[23];
    const float* pw     = (const float*)d_in[24];
    const float* pb     = (const float*)d_in[25];
    const float* kw     = (const float*)d_in[26];
    const float* kb     = (const float*)d_in[27];
    const float* vw     = (const float*)d_in[28];
    const float* vb     = (const float*)d_in[29];
    const float* cw     = (const float*)d_in[30];
    const float* cb     = (const float*)d_in[31];
    // d_in[32] = conn_idx -- unused: acts is a feat_sum broadcast, so the
    // gather/einsum collapses to feat_sum[b] * rowsum(conn_w)[n].

    float* ws = (float*)d_ws;
    float* out = (float*)d_out;

    prep_kernel<<<(PREP_TOTAL + 255) / 256, 256, 0, stream>>>(
        W_ih0, W_hh0, b_ih0, b_hh0, W_ih1, W_hh1, b_ih1, b_hh1,
        conn_w, sens, ws);

    lstm_fused<<<NB / 2, 1024, 0, stream>>>(
        x, ws, fp_w1, fp_b1, fp_w2, fp_b2, ws + OFF_FS);

    neuron_kernel<<<NB, 256, 0, stream>>>(
        ws + OFF_FS, ws + OFF_A, thr, ws + OFF_NO, ws + OFF_MEANS);

    {
        dim3 grid(NB / 32, 256 / 32);
        gemm_h1<<<grid, 256, 0, stream>>>(
            ws + OFF_NO, int_w1, int_b1, ws + OFF_H1);
    }

    tail_kernel<<<NB, 64, 0, stream>>>(
        ws + OFF_H1, int_w2, int_b2, int_w3, int_b3,
        tw, tb, pw, pb, kw, kb, vw, vb, cw, cb,
        ws + OFF_MEANS, out);
}